// Round 3
// baseline (75.644 us; speedup 1.0000x reference)
//
#include <hip/hip_runtime.h>

// out[b,u] = prod_f(inputs[b,f] * weight[f,u]) + bias[u]
//          = (prod_f inputs[b,f]) * (prod_f weight[f,u]) + bias[u]
// B=32768, F=32, U=256.
// R5: zero-sync, zero-LDS. Each wave owns 8 rows end-to-end; no
// __syncthreads, no shared memory, waves fully independent so stores issue
// as soon as each wave's data is ready (no barrier tail).
// - Pw: each lane owns 4 columns, computed from f32x4 weight loads. Weight
//   is 32KB = exactly L1 size -> L1-hot after first wave warms it.
// - Pin: in-register xor-shuffle product over 8-lane groups.
// - NT load for input / NT store for output (touch-once) keep L1/L2
//   dedicated to weight.
// Mandatory traffic: 4MB in + 32MB out -> ~5.8us at 6.3 TB/s achievable.

#define F 32
#define U 256
#define ROWS_PER_BLOCK 32   // 4 waves x 8 rows

typedef float f32x4 __attribute__((ext_vector_type(4)));

__global__ __launch_bounds__(256)
void fused_kernel(const float* __restrict__ inp,
                  const float* __restrict__ weight,
                  const float* __restrict__ bias,
                  float* __restrict__ out) {
  const int tid  = threadIdx.x;
  const int lane = tid & 63;
  const int wave = tid >> 6;
  // this wave's first row: 8 rows per wave, 32 per block
  const int base = blockIdx.x * ROWS_PER_BLOCK + wave * 8;

  // ---- input: issue FIRST (cold HBM). 8 rows = 1KB contiguous per wave;
  // lane l covers row base+(l>>3), floats (l&7)*4 .. +3. ----
  const f32x4 x = __builtin_nontemporal_load(
      (const f32x4*)(inp + (size_t)base * F + lane * 4));

  // ---- bias for this lane's 4 columns ----
  const f32x4 b4 = *(const f32x4*)(bias + lane * 4);

  // ---- Pw: lane owns columns lane*4..lane*4+3. 32 x f32x4 loads, same
  // addresses for every wave/block -> L1-hot (weight fits L1 exactly). ----
  f32x4 w4 = {1.0f, 1.0f, 1.0f, 1.0f};
#pragma unroll
  for (int f = 0; f < F; ++f) {
    const f32x4 wf = *(const f32x4*)(weight + f * U + lane * 4);
    w4 *= wf;
  }

  // ---- Pin: xor-shuffle product over the 8-lane group. After this, every
  // lane in group g holds pin[base + g]. ----
  float m = x.x * x.y * x.z * x.w;
  m *= __shfl_xor(m, 1);
  m *= __shfl_xor(m, 2);
  m *= __shfl_xor(m, 4);

  // ---- epilogue: 8 rows, 1KB per NT store step, fully coalesced ----
#pragma unroll
  for (int g = 0; g < 8; ++g) {
    const float pin = __shfl(m, g * 8);  // wave-wide broadcast
    f32x4 o;
    o.x = pin * w4.x + b4.x;
    o.y = pin * w4.y + b4.y;
    o.z = pin * w4.z + b4.z;
    o.w = pin * w4.w + b4.w;
    __builtin_nontemporal_store(o, (f32x4*)(out + (size_t)(base + g) * U + lane * 4));
  }
}

extern "C" void kernel_launch(void* const* d_in, const int* in_sizes, int n_in,
                              void* d_out, int out_size, void* d_ws, size_t ws_size,
                              hipStream_t stream) {
  const float* inp    = (const float*)d_in[0];  // [B, F]
  const float* weight = (const float*)d_in[1];  // [F, U]
  // d_in[2] = weight_selector: dead code in the reference, unused
  const float* bias   = (const float*)d_in[3];  // [U]
  float* out = (float*)d_out;                   // [B, U]

  const int B = in_sizes[0] / F;
  fused_kernel<<<B / ROWS_PER_BLOCK, 256, 0, stream>>>(inp, weight, bias, out);
}

// Round 4
// 72.039 us; speedup vs baseline: 1.0500x; 1.0500x over previous
//
#include <hip/hip_runtime.h>

// out[b,u] = prod_f(inputs[b,f] * weight[f,u]) + bias[u]
//          = (prod_f inputs[b,f]) * (prod_f weight[f,u]) + bias[u]
// B=32768, F=32, U=256.
// R6 = revert to R3, the best-measured variant (71.99 us).
// Evidence ledger: R4 (1-barrier shuffle) == R3 within fill jitter;
// R5 (zero-LDS, per-lane weight columns) = real -3.6us regression from 4x
// weight L2 traffic (128 MB vs 32 MB). Weight products MUST be computed
// once per block by 256 threads (one column each, 32KB/block total).
// NT input load + NT output stores keep L2 dedicated to the weight matrix.
// Mandatory traffic: 4MB in + 32MB out -> ~5.8us at 6.3 TB/s achievable;
// kernel is under harness measurement resolution beyond this point.

#define F 32
#define U 256
#define ROWS_PER_BLOCK 32

typedef float f32x4 __attribute__((ext_vector_type(4)));

__global__ __launch_bounds__(256)
void fused_kernel(const float* __restrict__ inp,
                  const float* __restrict__ weight,
                  const float* __restrict__ bias,
                  float* __restrict__ out) {
  __shared__ float partial[256];            // per-float4 products of input tile
  __shared__ float pin_s[ROWS_PER_BLOCK];   // per-row input products
  __shared__ float pw_s[U];                 // per-column weight products

  const int tid = threadIdx.x;
  const int base = blockIdx.x * ROWS_PER_BLOCK;

  // ---- input tile: issue FIRST (cold HBM, longest latency; overlaps Pw) ----
  // 32 rows x 32 floats = 4KB, one float4 per thread. Read exactly once ->
  // non-temporal, don't allocate in L2.
  const f32x4 x = __builtin_nontemporal_load(
      (const f32x4*)(inp + (size_t)base * F + tid * 4));

  // ---- Pw[u]: each thread owns one column; loads coalesced across lanes.
  // 32KB per block total (NOT per wave - see R5 post-mortem). ----
  {
    float p = 1.0f;
#pragma unroll
    for (int f = 0; f < F; ++f) p *= weight[f * U + tid];
    pw_s[tid] = p;
  }

  partial[tid] = x.x * x.y * x.z * x.w;
  __syncthreads();

  // ---- row products: 8 partials per row ----
  if (tid < ROWS_PER_BLOCK) {
    float p = 1.0f;
#pragma unroll
    for (int k = 0; k < 8; ++k) p *= partial[tid * 8 + k];
    pin_s[tid] = p;
  }
  __syncthreads();

  // ---- epilogue: wave w stores rows {w, w+4, ..., w+28}, 1KB/wave/step ----
  // Output is write-once streaming: NT stores bypass L2 allocate so the
  // 32MB stream doesn't evict the weight working set.
  const int lane = tid & 63;
  const int wave = tid >> 6;
  const f32x4 w4 = *(const f32x4*)(&pw_s[lane * 4]);
  const f32x4 b4 = *(const f32x4*)(bias + lane * 4);
#pragma unroll
  for (int g = 0; g < 8; ++g) {
    const int r = g * 4 + wave;
    const float p = pin_s[r];  // LDS broadcast
    f32x4 o;
    o.x = p * w4.x + b4.x;
    o.y = p * w4.y + b4.y;
    o.z = p * w4.z + b4.z;
    o.w = p * w4.w + b4.w;
    __builtin_nontemporal_store(o, (f32x4*)(out + (size_t)(base + r) * U + lane * 4));
  }
}

extern "C" void kernel_launch(void* const* d_in, const int* in_sizes, int n_in,
                              void* d_out, int out_size, void* d_ws, size_t ws_size,
                              hipStream_t stream) {
  const float* inp    = (const float*)d_in[0];  // [B, F]
  const float* weight = (const float*)d_in[1];  // [F, U]
  // d_in[2] = weight_selector: dead code in the reference, unused
  const float* bias   = (const float*)d_in[3];  // [U]
  float* out = (float*)d_out;                   // [B, U]

  const int B = in_sizes[0] / F;
  fused_kernel<<<B / ROWS_PER_BLOCK, 256, 0, stream>>>(inp, weight, bias, out);
}